// Round 12
// baseline (768.215 us; speedup 1.0000x reference)
//
#include <hip/hip_runtime.h>
#include <stdint.h>

typedef __attribute__((ext_vector_type(8))) short short8;
typedef __attribute__((ext_vector_type(4))) float floatx4;
typedef __attribute__((ext_vector_type(4))) int intx4;
typedef __attribute__((ext_vector_type(4))) uint32_t uintx4;

__device__ __forceinline__ float bf2f(uint32_t u16) {
    union { uint32_t i; float f; } cv; cv.i = u16 << 16; return cv.f;
}
__device__ __forceinline__ uint32_t f2bf(float f) {
    union { float f; uint32_t i; } cv; cv.f = f;
    uint32_t r = cv.i + 0x7FFFu + ((cv.i >> 16) & 1u);  // RTN-even
    return r >> 16;
}

template <typename T>
__device__ __forceinline__ void gload_lds16(const T* g, T* lds) {
    __builtin_amdgcn_global_load_lds((const __attribute__((address_space(1))) uint32_t*)g,
                                     (__attribute__((address_space(3))) uint32_t*)lds, 16, 0, 0);
}

#define MFMA16(a, b, c) __builtin_amdgcn_mfma_f32_16x16x32_bf16((a), (b), (c), 0, 0, 0)
#define CFENCE asm volatile("" ::: "memory")

// ---------------- pass 1: merged prep (dequant W + convert x) --------------
// blocks [0, dqBlocks): AWQ int4 -> W bf16; blocks [dqBlocks, ..): x f32->bf16.
// AWQ nibble order [0,4,1,5,2,6,3,7] -> element shifts {0,16,4,20,8,24,12,28}
__global__ __launch_bounds__(256)
void prep_kernel(const int* __restrict__ qweight,
                 const int* __restrict__ qzeros,
                 const float* __restrict__ scales,   // [O/G, I] f32
                 uint32_t* __restrict__ W_w,         // [O, I/2] u32 words
                 const float* __restrict__ x,
                 uint32_t* __restrict__ Xb_w,        // [M, I/2] u32 words
                 int I, int G, int dqBlocks, long long nwords) {
    if ((int)blockIdx.x < dqBlocks) {
        const int wpr = I >> 3;
        int idx = blockIdx.x * 256 + threadIdx.x;   // flat over O * wpr
        const int o = idx / wpr;
        const int wi = idx - o * wpr;
        const int g = o / G;
        const int qw = qweight[(size_t)o * wpr + wi];
        const int zw = qzeros[(size_t)g * wpr + wi];
        const float* sp = scales + (size_t)g * I + wi * 8;
        floatx4 s0 = *(const floatx4*)sp;
        floatx4 s1 = *(const floatx4*)(sp + 4);
        const int sh[8] = {0, 16, 4, 20, 8, 24, 12, 28};
        uintx4 ov;
#pragma unroll
        for (int p = 0; p < 4; ++p) {
            int jl = 2 * p, jh = 2 * p + 1;
            int wl = (qw >> sh[jl]) & 0xF, zl = (zw >> sh[jl]) & 0xF;
            int wh = (qw >> sh[jh]) & 0xF, zh = (zw >> sh[jh]) & 0xF;
            float sl = (jl < 4) ? s0[jl] : s1[jl - 4];
            float shv = (jh < 4) ? s0[jh] : s1[jh - 4];
            ov[p] = f2bf(sl * (float)(wl - zl)) | (f2bf(shv * (float)(wh - zh)) << 16);
        }
        *(uintx4*)(W_w + (size_t)o * (I >> 1) + wi * 4) = ov;
    } else {
        long long t = (long long)(blockIdx.x - dqBlocks) * 256 + threadIdx.x;
        long long w0 = t * 4;
        if (w0 >= nwords) return;
        floatx4 v0 = *(const floatx4*)(x + w0 * 2);
        floatx4 v1 = *(const floatx4*)(x + w0 * 2 + 4);
        uintx4 ov;
#pragma unroll
        for (int p = 0; p < 2; ++p) {
            ov[p]     = f2bf(v0[2 * p]) | (f2bf(v0[2 * p + 1]) << 16);
            ov[p + 2] = f2bf(v1[2 * p]) | (f2bf(v1[2 * p + 1]) << 16);
        }
        *(uintx4*)(Xb_w + w0) = ov;
    }
}

// ---- pass 2: 256x256 GEMM, deep-prefetch single-barrier pipeline ----------
// r6 compute body unchanged. LDS 160KB: A triple-buffered (3x32KB), B double
// (2x32KB). Per iter: {vmcnt(4); s_barrier; issue B(t+1), A(t+2); ds_read +
// 64 MFMA on A(t%3)/B(t&1)}. In-order vmcnt retirement: at wait(t) queue =
// [A(t)4, B(t)4, A(t+1)4] -> vmcnt(4) retires A(t),B(t), leaves A(t+1) in
// flight ACROSS the barrier. WAR-safe: each wave's ds_reads are lgkm-retired
// by its MFMAs before it reaches the barrier; staging writes land after.
__global__ __launch_bounds__(512, 2)
void gemm_bf16_256(const ushort* __restrict__ A,   // [M,K] bf16
                   const ushort* __restrict__ Bw,  // [N,K] bf16 (B^T)
                   const float* __restrict__ bias,
                   float* __restrict__ C,
                   int M, int N, int K) {
    __shared__ ushort sh[81920];  // 160KB: A bufs @0/16384/32768, B @49152/65536

    const int tid = threadIdx.x;
    const int lane = tid & 63;
    const int wave = tid >> 6;
    const int wm = wave >> 2;   // 0..1
    const int wn = wave & 3;    // 0..3

    // bijective XCD remap (m204)
    const int nwg = gridDim.x * gridDim.y;
    const int orig = blockIdx.y * gridDim.x + blockIdx.x;
    const int q = nwg >> 3, r = nwg & 7;
    const int xcd = orig & 7, off = orig >> 3;
    const int wgid = (xcd < r ? xcd * (q + 1) : r * (q + 1) + (xcd - r) * q) + off;
    const int by = wgid / gridDim.x;
    const int bx = wgid % gridDim.x;
    const int m0 = by * 256, n0 = bx * 256;

    // staging map: thread -> (row = pass*64 + tid>>3, swizzled col)
    const int srow = tid >> 3, sslot = tid & 7;
    const int scol = ((sslot ^ (srow & 7)) << 3);     // pre-swizzled global col
    const ushort* gA0 = A + (size_t)(m0 + srow) * K + scol;
    const ushort* gB0 = Bw + (size_t)(n0 + srow) * K + scol;

#define STAGE_A(bufa, tt) do {                                                   \
    const ushort* ga_ = gA0 + (size_t)(tt) * 64;                                 \
    ushort* da_ = &sh[(bufa) * 16384 + tid * 8];                                 \
    _Pragma("unroll")                                                            \
    for (int p_ = 0; p_ < 4; ++p_)                                               \
        gload_lds16(ga_ + (size_t)p_ * 64 * K, da_ + p_ * 4096);                 \
} while (0)
#define STAGE_B(bufb, tt) do {                                                   \
    const ushort* gb_ = gB0 + (size_t)(tt) * 64;                                 \
    ushort* db_ = &sh[49152 + (bufb) * 16384 + tid * 8];                         \
    _Pragma("unroll")                                                            \
    for (int p_ = 0; p_ < 4; ++p_)                                               \
        gload_lds16(gb_ + (size_t)p_ * 64 * K, db_ + p_ * 4096);                 \
} while (0)

    // fragment read map (swizzled)
    const int fr = lane & 15;
    const int fk = (lane >> 4) * 8;
    const int sx = (fr & 7) * 8;
    const int colsw0 = fk ^ sx;           // kk=0
    const int colsw1 = (32 + fk) ^ sx;    // kk=1
    const int arow = wm * 128 + fr;
    const int brow = wn * 64 + fr;

    floatx4 acc[2][2][4][2];
#pragma unroll
    for (int a = 0; a < 2; ++a)
#pragma unroll
        for (int b = 0; b < 2; ++b)
#pragma unroll
            for (int c = 0; c < 4; ++c)
#pragma unroll
                for (int d = 0; d < 2; ++d) acc[a][b][c][d] = (floatx4){0.f, 0.f, 0.f, 0.f};

    const int NT = K >> 6;  // launcher guarantees NT >= 2

    // prologue: issue A(0), B(0), A(1)  (age order matches steady state)
    STAGE_A(0, 0);
    STAGE_B(0, 0);
    STAGE_A(1, 1);

    int abuf = 0;
#pragma unroll 1
    for (int t = 0; t < NT; ++t) {
        // counted wait: retire A(t),B(t); keep A(t+1) in flight across barrier
        if (t == NT - 1) asm volatile("s_waitcnt vmcnt(0)" ::: "memory");
        else             asm volatile("s_waitcnt vmcnt(4)" ::: "memory");
        CFENCE; __builtin_amdgcn_s_barrier(); CFENCE;

        // issue next stages (B first, then A: keeps queue age-ordered)
        if (t + 1 < NT) STAGE_B((t + 1) & 1, t + 1);
        if (t + 2 < NT) { int a2 = abuf + 2; if (a2 >= 3) a2 -= 3; STAGE_A(a2, t + 2); }

        const int ab = abuf * 16384;
        const int bb = 49152 + (t & 1) * 16384;

        short8 bfr[2][2][2];  // [qn][ni][kk]
#pragma unroll
        for (int qn = 0; qn < 2; ++qn)
#pragma unroll
            for (int ni = 0; ni < 2; ++ni) {
                int rowe = (brow + qn * 32 + ni * 16) * 64;
                bfr[qn][ni][0] = *(const short8*)&sh[bb + rowe + colsw0];
                bfr[qn][ni][1] = *(const short8*)&sh[bb + rowe + colsw1];
            }

#pragma unroll
        for (int qm = 0; qm < 2; ++qm) {
            short8 af[4][2];
#pragma unroll
            for (int mi = 0; mi < 4; ++mi) {
                int rowe = (arow + qm * 64 + mi * 16) * 64;
                af[mi][0] = *(const short8*)&sh[ab + rowe + colsw0];
                af[mi][1] = *(const short8*)&sh[ab + rowe + colsw1];
            }
#pragma unroll
            for (int qn = 0; qn < 2; ++qn) {
                __builtin_amdgcn_s_setprio(1);
#pragma unroll
                for (int mi = 0; mi < 4; ++mi)
#pragma unroll
                    for (int ni = 0; ni < 2; ++ni) {
                        acc[qm][qn][mi][ni] = MFMA16(af[mi][0], bfr[qn][ni][0], acc[qm][qn][mi][ni]);
                        acc[qm][qn][mi][ni] = MFMA16(af[mi][1], bfr[qn][ni][1], acc[qm][qn][mi][ni]);
                    }
                __builtin_amdgcn_s_setprio(0);
            }
        }
        ++abuf; if (abuf == 3) abuf = 0;
    }

    // epilogue: C = acc + bias (f32), plain stores
    float bv[2][2];
#pragma unroll
    for (int qn = 0; qn < 2; ++qn)
#pragma unroll
        for (int ni = 0; ni < 2; ++ni)
            bv[qn][ni] = bias[n0 + wn * 64 + qn * 32 + ni * 16 + fr];
    const int crow_base = m0 + wm * 128 + (lane >> 4) * 4;
    const int ccol_base = n0 + wn * 64 + fr;
#pragma unroll
    for (int qm = 0; qm < 2; ++qm)
#pragma unroll
        for (int qn = 0; qn < 2; ++qn)
#pragma unroll
            for (int mi = 0; mi < 4; ++mi)
#pragma unroll
                for (int ni = 0; ni < 2; ++ni)
#pragma unroll
                    for (int rr = 0; rr < 4; ++rr)
                        C[(size_t)(crow_base + qm * 64 + mi * 16 + rr) * N +
                          ccol_base + qn * 32 + ni * 16] =
                            acc[qm][qn][mi][ni][rr] + bv[qn][ni];
#undef STAGE_A
#undef STAGE_B
}

// ---------------- fallback: fully fused (round-4 proven kernel) ----------
#define BM 128
#define BN 128
#define BK 64
__global__ __launch_bounds__(256)
void awq_gemm_fused(const float* __restrict__ x,
                    const int* __restrict__ qweight,
                    const int* __restrict__ qzeros,
                    const float* __restrict__ scales,
                    const float* __restrict__ bias,
                    float* __restrict__ C,
                    int M, int N, int K, int G) {
    __shared__ __align__(16) short As[BM * BK];
    __shared__ __align__(16) short Bs[BN * BK];

    const int tid = threadIdx.x;
    const int lane = tid & 63;
    const int wave = tid >> 6;
    const int wm = wave >> 1;
    const int wn = wave & 1;
    const int m0 = blockIdx.y * BM;
    const int n0 = blockIdx.x * BN;

    floatx4 acc[4][4];
#pragma unroll
    for (int i = 0; i < 4; ++i)
#pragma unroll
        for (int j = 0; j < 4; ++j) acc[i][j] = (floatx4){0.f, 0.f, 0.f, 0.f};

    const int srow = tid >> 3;
    const int scol = (tid & 7) * 8;
    const int fr = lane & 15;
    const int fk = (lane >> 4) * 8;
    const int rB = tid >> 1, hB = tid & 1;
    const int oB = n0 + rB, gB = oB / G;
    const int wpr = K >> 3;
    const int sh[8] = {0, 16, 4, 20, 8, 24, 12, 28};

    for (int k0 = 0; k0 < K; k0 += BK) {
#pragma unroll
        for (int p = 0; p < 4; ++p) {
            int r = p * 32 + srow;
            const float* gp = x + (size_t)(m0 + r) * K + k0 + scol;
            floatx4 v0 = *(const floatx4*)gp;
            floatx4 v1 = *(const floatx4*)(gp + 4);
            short8 ov;
#pragma unroll
            for (int j = 0; j < 4; ++j) {
                ov[j] = (short)f2bf(v0[j]);
                ov[j + 4] = (short)f2bf(v1[j]);
            }
            *(short8*)&As[r * BK + scol] = ov;
        }
        {
            const int kw0 = (k0 >> 3) + hB * 4;
            intx4 qw4 = *(const intx4*)(qweight + (size_t)oB * wpr + kw0);
            intx4 zw4 = *(const intx4*)(qzeros + (size_t)gB * wpr + kw0);
            const float* sp = scales + (size_t)gB * K + k0 + hB * 32;
#pragma unroll
            for (int wj = 0; wj < 4; ++wj) {
                floatx4 s0 = *(const floatx4*)(sp + wj * 8);
                floatx4 s1 = *(const floatx4*)(sp + wj * 8 + 4);
                int qw = qw4[wj], zw = zw4[wj];
                short8 ov;
#pragma unroll
                for (int j = 0; j < 8; ++j) {
                    int wv = (qw >> sh[j]) & 0xF;
                    int zv = (zw >> sh[j]) & 0xF;
                    float sj = (j < 4) ? s0[j] : s1[j - 4];
                    ov[j] = (short)f2bf(sj * (float)(wv - zv));
                }
                *(short8*)&Bs[rB * BK + hB * 32 + wj * 8] = ov;
            }
        }
        __syncthreads();

#pragma unroll
        for (int kk = 0; kk < 2; ++kk) {
            short8 af[4], bfr[4];
#pragma unroll
            for (int mi = 0; mi < 4; ++mi)
                af[mi] = *(const short8*)&As[(wm * 64 + mi * 16 + fr) * BK + kk * 32 + fk];
#pragma unroll
            for (int ni = 0; ni < 4; ++ni)
                bfr[ni] = *(const short8*)&Bs[(wn * 64 + ni * 16 + fr) * BK + kk * 32 + fk];
#pragma unroll
            for (int mi = 0; mi < 4; ++mi)
#pragma unroll
                for (int ni = 0; ni < 4; ++ni)
                    acc[mi][ni] = MFMA16(af[mi], bfr[ni], acc[mi][ni]);
        }
        __syncthreads();
    }

    float bv[4];
#pragma unroll
    for (int ni = 0; ni < 4; ++ni)
        bv[ni] = bias[n0 + wn * 64 + ni * 16 + fr];
    const int crow0 = m0 + wm * 64 + (lane >> 4) * 4;
    const int ccol0 = n0 + wn * 64 + fr;
#pragma unroll
    for (int mi = 0; mi < 4; ++mi)
#pragma unroll
        for (int ni = 0; ni < 4; ++ni)
#pragma unroll
            for (int r = 0; r < 4; ++r)
                C[(size_t)(crow0 + mi * 16 + r) * N + ccol0 + ni * 16] =
                    acc[mi][ni][r] + bv[ni];
}

extern "C" void kernel_launch(void* const* d_in, const int* in_sizes, int n_in,
                              void* d_out, int out_size, void* d_ws, size_t ws_size,
                              hipStream_t stream) {
    const float* x = (const float*)d_in[0];        // [M, K] f32 (fp16 upcast)
    const int* qweight = (const int*)d_in[1];      // [O, I/8]
    const int* qzeros = (const int*)d_in[2];       // [O/G, I/8]
    const float* scales = (const float*)d_in[3];   // [O/G, I] f32
    const float* bias = (const float*)d_in[4];     // [O] f32
    float* out = (float*)d_out;

    const int O = in_sizes[4];
    const int I = (int)(((long long)in_sizes[1] * 8) / O);
    const int M = (int)((long long)in_sizes[0] / I);
    const int G = (int)(((long long)O * I) / in_sizes[3]);

    const size_t wbytes = (size_t)O * I * 2;
    const size_t xbytes = (size_t)M * I * 2;

    if (ws_size >= wbytes + xbytes && (M % 256) == 0 && (O % 256) == 0 &&
        (I % 64) == 0 && I >= 128 && ((O * (I / 8)) % 256) == 0) {
        uint32_t* W_w = (uint32_t*)d_ws;
        uint32_t* X_w = (uint32_t*)((char*)d_ws + wbytes);
        long long nwords = (long long)M * I / 2;
        int dqBlocks = (O * (I / 8)) / 256;
        int cvBlocks = (int)((nwords / 4 + 255) / 256);
        prep_kernel<<<dqBlocks + cvBlocks, 256, 0, stream>>>(
            qweight, qzeros, scales, W_w, x, X_w, I, G, dqBlocks, nwords);
        dim3 grid(O / 256, M / 256);
        gemm_bf16_256<<<grid, dim3(512), 0, stream>>>(
            (const ushort*)X_w, (const ushort*)W_w, bias, out, M, O, I);
    } else {
        dim3 grid(O / BN, M / BM);
        awq_gemm_fused<<<grid, dim3(256), 0, stream>>>(
            x, qweight, qzeros, scales, bias, out, M, O, I, G);
    }
}

// Round 13
// 761.678 us; speedup vs baseline: 1.0086x; 1.0086x over previous
//
#include <hip/hip_runtime.h>
#include <stdint.h>

typedef __attribute__((ext_vector_type(8))) short short8;
typedef __attribute__((ext_vector_type(4))) float floatx4;
typedef __attribute__((ext_vector_type(4))) int intx4;
typedef __attribute__((ext_vector_type(4))) uint32_t uintx4;

__device__ __forceinline__ float bf2f(uint32_t u16) {
    union { uint32_t i; float f; } cv; cv.i = u16 << 16; return cv.f;
}
__device__ __forceinline__ uint32_t f2bf(float f) {
    union { float f; uint32_t i; } cv; cv.f = f;
    uint32_t r = cv.i + 0x7FFFu + ((cv.i >> 16) & 1u);  // RTN-even
    return r >> 16;
}

template <typename T>
__device__ __forceinline__ void gload_lds16(const T* g, T* lds) {
    __builtin_amdgcn_global_load_lds((const __attribute__((address_space(1))) uint32_t*)g,
                                     (__attribute__((address_space(3))) uint32_t*)lds, 16, 0, 0);
}

#define MFMA16(a, b, c) __builtin_amdgcn_mfma_f32_16x16x32_bf16((a), (b), (c), 0, 0, 0)

// ---------------- pass 1: merged prep (dequant W + convert x) --------------
// blocks [0, dqBlocks): AWQ int4 -> W bf16; blocks [dqBlocks, ..): x f32->bf16.
// AWQ nibble order [0,4,1,5,2,6,3,7] -> element shifts {0,16,4,20,8,24,12,28}
__global__ __launch_bounds__(256)
void prep_kernel(const int* __restrict__ qweight,
                 const int* __restrict__ qzeros,
                 const float* __restrict__ scales,   // [O/G, I] f32
                 uint32_t* __restrict__ W_w,         // [O, I/2] u32 words
                 const float* __restrict__ x,
                 uint32_t* __restrict__ Xb_w,        // [M, I/2] u32 words
                 int I, int G, int dqBlocks, long long nwords) {
    if ((int)blockIdx.x < dqBlocks) {
        const int wpr = I >> 3;
        int idx = blockIdx.x * 256 + threadIdx.x;   // flat over O * wpr
        const int o = idx / wpr;
        const int wi = idx - o * wpr;
        const int g = o / G;
        const int qw = qweight[(size_t)o * wpr + wi];
        const int zw = qzeros[(size_t)g * wpr + wi];
        const float* sp = scales + (size_t)g * I + wi * 8;
        floatx4 s0 = *(const floatx4*)sp;
        floatx4 s1 = *(const floatx4*)(sp + 4);
        const int sh[8] = {0, 16, 4, 20, 8, 24, 12, 28};
        uintx4 ov;
#pragma unroll
        for (int p = 0; p < 4; ++p) {
            int jl = 2 * p, jh = 2 * p + 1;
            int wl = (qw >> sh[jl]) & 0xF, zl = (zw >> sh[jl]) & 0xF;
            int wh = (qw >> sh[jh]) & 0xF, zh = (zw >> sh[jh]) & 0xF;
            float sl = (jl < 4) ? s0[jl] : s1[jl - 4];
            float shv = (jh < 4) ? s0[jh] : s1[jh - 4];
            ov[p] = f2bf(sl * (float)(wl - zl)) | (f2bf(shv * (float)(wh - zh)) << 16);
        }
        *(uintx4*)(W_w + (size_t)o * (I >> 1) + wi * 4) = ov;
    } else {
        long long t = (long long)(blockIdx.x - dqBlocks) * 256 + threadIdx.x;
        long long w0 = t * 4;
        if (w0 >= nwords) return;
        floatx4 v0 = *(const floatx4*)(x + w0 * 2);
        floatx4 v1 = *(const floatx4*)(x + w0 * 2 + 4);
        uintx4 ov;
#pragma unroll
        for (int p = 0; p < 2; ++p) {
            ov[p]     = f2bf(v0[2 * p]) | (f2bf(v0[2 * p + 1]) << 16);
            ov[p + 2] = f2bf(v1[2 * p]) | (f2bf(v1[2 * p + 1]) << 16);
        }
        *(uintx4*)(Xb_w + w0) = ov;
    }
}

// ---------------- pass 2: 256x256 pipelined swizzled GEMM (r6 structure) ---
// C[M,N] = A[M,K] * Bw[N,K]^T + bias. 8 waves (2M x 4N), BK=64, 128KB
// double-buffered LDS, stage-after-barrier pipeline (1 barrier/K-tile),
// T2 XOR-swizzle via pre-swizzled global source, bijective XCD remap.
// A/B vs r6: s_setprio REMOVED (m190: setprio negative on lockstep GEMM).
__global__ __launch_bounds__(512, 2)
void gemm_bf16_256(const ushort* __restrict__ A,   // [M,K] bf16
                   const ushort* __restrict__ Bw,  // [N,K] bf16 (B^T)
                   const float* __restrict__ bias,
                   float* __restrict__ C,
                   int M, int N, int K) {
    __shared__ ushort sh[65536];  // 128 KB: [buf][A 16384 | B 16384] elems

    const int tid = threadIdx.x;
    const int lane = tid & 63;
    const int wave = tid >> 6;
    const int wm = wave >> 2;   // 0..1
    const int wn = wave & 3;    // 0..3

    // bijective XCD remap (m204)
    const int nwg = gridDim.x * gridDim.y;
    const int orig = blockIdx.y * gridDim.x + blockIdx.x;
    const int q = nwg >> 3, r = nwg & 7;
    const int xcd = orig & 7, off = orig >> 3;
    const int wgid = (xcd < r ? xcd * (q + 1) : r * (q + 1) + (xcd - r) * q) + off;
    const int by = wgid / gridDim.x;
    const int bx = wgid % gridDim.x;
    const int m0 = by * 256, n0 = bx * 256;

    // staging map: thread -> (row = pass*64 + tid>>3, swizzled col)
    const int srow = tid >> 3, sslot = tid & 7;
    const int scol = ((sslot ^ (srow & 7)) << 3);     // pre-swizzled global col
    const ushort* gA0 = A + (size_t)(m0 + srow) * K + scol;
    const ushort* gB0 = Bw + (size_t)(n0 + srow) * K + scol;

    // fragment read map (swizzled)
    const int fr = lane & 15;
    const int fk = (lane >> 4) * 8;
    const int sx = (fr & 7) * 8;
    const int colsw0 = fk ^ sx;           // kk=0
    const int colsw1 = (32 + fk) ^ sx;    // kk=1
    const int arow = wm * 128 + fr;
    const int brow = wn * 64 + fr;

    floatx4 acc[2][2][4][2];
#pragma unroll
    for (int a = 0; a < 2; ++a)
#pragma unroll
        for (int b = 0; b < 2; ++b)
#pragma unroll
            for (int c = 0; c < 4; ++c)
#pragma unroll
                for (int d = 0; d < 2; ++d) acc[a][b][c][d] = (floatx4){0.f, 0.f, 0.f, 0.f};

    const int NT = K >> 6;

    // prologue: stage tile 0 into buf 0
    {
        ushort* da = &sh[tid * 8];
        ushort* db = &sh[16384 + tid * 8];
#pragma unroll
        for (int p = 0; p < 4; ++p) {
            gload_lds16(gA0 + (size_t)p * 64 * K, da + p * 4096);
            gload_lds16(gB0 + (size_t)p * 64 * K, db + p * 4096);
        }
    }

#pragma unroll 1
    for (int t = 0; t < NT; ++t) {
        const int p = t & 1;
        __syncthreads();  // drains vmcnt: tile t landed; fences t-1 reads

        if (t + 1 < NT) {  // stage tile t+1 into buf p^1 (lands during compute)
            const int k1 = (t + 1) << 6;
            const ushort* ga = gA0 + k1;
            const ushort* gb = gB0 + k1;
            ushort* da = &sh[(p ^ 1) * 32768 + tid * 8];
            ushort* db = &sh[(p ^ 1) * 32768 + 16384 + tid * 8];
#pragma unroll
            for (int ps = 0; ps < 4; ++ps) {
                gload_lds16(ga + (size_t)ps * 64 * K, da + ps * 4096);
                gload_lds16(gb + (size_t)ps * 64 * K, db + ps * 4096);
            }
        }

        const int ab = p * 32768, bb = ab + 16384;

        short8 bfr[2][2][2];  // [qn][ni][kk]
#pragma unroll
        for (int qn = 0; qn < 2; ++qn)
#pragma unroll
            for (int ni = 0; ni < 2; ++ni) {
                int rowe = (brow + qn * 32 + ni * 16) * 64;
                bfr[qn][ni][0] = *(const short8*)&sh[bb + rowe + colsw0];
                bfr[qn][ni][1] = *(const short8*)&sh[bb + rowe + colsw1];
            }

#pragma unroll
        for (int qm = 0; qm < 2; ++qm) {
            short8 af[4][2];
#pragma unroll
            for (int mi = 0; mi < 4; ++mi) {
                int rowe = (arow + qm * 64 + mi * 16) * 64;
                af[mi][0] = *(const short8*)&sh[ab + rowe + colsw0];
                af[mi][1] = *(const short8*)&sh[ab + rowe + colsw1];
            }
#pragma unroll
            for (int qn = 0; qn < 2; ++qn)
#pragma unroll
                for (int mi = 0; mi < 4; ++mi)
#pragma unroll
                    for (int ni = 0; ni < 2; ++ni) {
                        acc[qm][qn][mi][ni] = MFMA16(af[mi][0], bfr[qn][ni][0], acc[qm][qn][mi][ni]);
                        acc[qm][qn][mi][ni] = MFMA16(af[mi][1], bfr[qn][ni][1], acc[qm][qn][mi][ni]);
                    }
        }
    }

    // epilogue: C = acc + bias (f32)
    float bv[2][2];
#pragma unroll
    for (int qn = 0; qn < 2; ++qn)
#pragma unroll
        for (int ni = 0; ni < 2; ++ni)
            bv[qn][ni] = bias[n0 + wn * 64 + qn * 32 + ni * 16 + fr];
    const int crow_base = m0 + wm * 128 + (lane >> 4) * 4;
    const int ccol_base = n0 + wn * 64 + fr;
#pragma unroll
    for (int qm = 0; qm < 2; ++qm)
#pragma unroll
        for (int qn = 0; qn < 2; ++qn)
#pragma unroll
            for (int mi = 0; mi < 4; ++mi)
#pragma unroll
                for (int ni = 0; ni < 2; ++ni)
#pragma unroll
                    for (int rr = 0; rr < 4; ++rr)
                        C[(size_t)(crow_base + qm * 64 + mi * 16 + rr) * N +
                          ccol_base + qn * 32 + ni * 16] =
                            acc[qm][qn][mi][ni][rr] + bv[qn][ni];
}

// ---------------- fallback: fully fused (round-4 proven kernel) ----------
#define BM 128
#define BN 128
#define BK 64
__global__ __launch_bounds__(256)
void awq_gemm_fused(const float* __restrict__ x,
                    const int* __restrict__ qweight,
                    const int* __restrict__ qzeros,
                    const float* __restrict__ scales,
                    const float* __restrict__ bias,
                    float* __restrict__ C,
                    int M, int N, int K, int G) {
    __shared__ __align__(16) short As[BM * BK];
    __shared__ __align__(16) short Bs[BN * BK];

    const int tid = threadIdx.x;
    const int lane = tid & 63;
    const int wave = tid >> 6;
    const int wm = wave >> 1;
    const int wn = wave & 1;
    const int m0 = blockIdx.y * BM;
    const int n0 = blockIdx.x * BN;

    floatx4 acc[4][4];
#pragma unroll
    for (int i = 0; i < 4; ++i)
#pragma unroll
        for (int j = 0; j < 4; ++j) acc[i][j] = (floatx4){0.f, 0.f, 0.f, 0.f};

    const int srow = tid >> 3;
    const int scol = (tid & 7) * 8;
    const int fr = lane & 15;
    const int fk = (lane >> 4) * 8;
    const int rB = tid >> 1, hB = tid & 1;
    const int oB = n0 + rB, gB = oB / G;
    const int wpr = K >> 3;
    const int sh[8] = {0, 16, 4, 20, 8, 24, 12, 28};

    for (int k0 = 0; k0 < K; k0 += BK) {
#pragma unroll
        for (int p = 0; p < 4; ++p) {
            int r = p * 32 + srow;
            const float* gp = x + (size_t)(m0 + r) * K + k0 + scol;
            floatx4 v0 = *(const floatx4*)gp;
            floatx4 v1 = *(const floatx4*)(gp + 4);
            short8 ov;
#pragma unroll
            for (int j = 0; j < 4; ++j) {
                ov[j] = (short)f2bf(v0[j]);
                ov[j + 4] = (short)f2bf(v1[j]);
            }
            *(short8*)&As[r * BK + scol] = ov;
        }
        {
            const int kw0 = (k0 >> 3) + hB * 4;
            intx4 qw4 = *(const intx4*)(qweight + (size_t)oB * wpr + kw0);
            intx4 zw4 = *(const intx4*)(qzeros + (size_t)gB * wpr + kw0);
            const float* sp = scales + (size_t)gB * K + k0 + hB * 32;
#pragma unroll
            for (int wj = 0; wj < 4; ++wj) {
                floatx4 s0 = *(const floatx4*)(sp + wj * 8);
                floatx4 s1 = *(const floatx4*)(sp + wj * 8 + 4);
                int qw = qw4[wj], zw = zw4[wj];
                short8 ov;
#pragma unroll
                for (int j = 0; j < 8; ++j) {
                    int wv = (qw >> sh[j]) & 0xF;
                    int zv = (zw >> sh[j]) & 0xF;
                    float sj = (j < 4) ? s0[j] : s1[j - 4];
                    ov[j] = (short)f2bf(sj * (float)(wv - zv));
                }
                *(short8*)&Bs[rB * BK + hB * 32 + wj * 8] = ov;
            }
        }
        __syncthreads();

#pragma unroll
        for (int kk = 0; kk < 2; ++kk) {
            short8 af[4], bfr[4];
#pragma unroll
            for (int mi = 0; mi < 4; ++mi)
                af[mi] = *(const short8*)&As[(wm * 64 + mi * 16 + fr) * BK + kk * 32 + fk];
#pragma unroll
            for (int ni = 0; ni < 4; ++ni)
                bfr[ni] = *(const short8*)&Bs[(wn * 64 + ni * 16 + fr) * BK + kk * 32 + fk];
#pragma unroll
            for (int mi = 0; mi < 4; ++mi)
#pragma unroll
                for (int ni = 0; ni < 4; ++ni)
                    acc[mi][ni] = MFMA16(af[mi], bfr[ni], acc[mi][ni]);
        }
        __syncthreads();
    }

    float bv[4];
#pragma unroll
    for (int ni = 0; ni < 4; ++ni)
        bv[ni] = bias[n0 + wn * 64 + ni * 16 + fr];
    const int crow0 = m0 + wm * 64 + (lane >> 4) * 4;
    const int ccol0 = n0 + wn * 64 + fr;
#pragma unroll
    for (int mi = 0; mi < 4; ++mi)
#pragma unroll
        for (int ni = 0; ni < 4; ++ni)
#pragma unroll
            for (int r = 0; r < 4; ++r)
                C[(size_t)(crow0 + mi * 16 + r) * N + ccol0 + ni * 16] =
                    acc[mi][ni][r] + bv[ni];
}

extern "C" void kernel_launch(void* const* d_in, const int* in_sizes, int n_in,
                              void* d_out, int out_size, void* d_ws, size_t ws_size,
                              hipStream_t stream) {
    const float* x = (const float*)d_in[0];        // [M, K] f32 (fp16 upcast)
    const int* qweight = (const int*)d_in[1];      // [O, I/8]
    const int* qzeros = (const int*)d_in[2];       // [O/G, I/8]
    const float* scales = (const float*)d_in[3];   // [O/G, I] f32
    const float* bias = (const float*)d_in[4];     // [O] f32
    float* out = (float*)d_out;

    const int O = in_sizes[4];
    const int I = (int)(((long long)in_sizes[1] * 8) / O);
    const int M = (int)((long long)in_sizes[0] / I);
    const int G = (int)(((long long)O * I) / in_sizes[3]);

    const size_t wbytes = (size_t)O * I * 2;
    const size_t xbytes = (size_t)M * I * 2;

    if (ws_size >= wbytes + xbytes && (M % 256) == 0 && (O % 256) == 0 &&
        (I % 64) == 0 && ((O * (I / 8)) % 256) == 0) {
        uint32_t* W_w = (uint32_t*)d_ws;
        uint32_t* X_w = (uint32_t*)((char*)d_ws + wbytes);
        long long nwords = (long long)M * I / 2;
        int dqBlocks = (O * (I / 8)) / 256;
        int cvBlocks = (int)((nwords / 4 + 255) / 256);
        prep_kernel<<<dqBlocks + cvBlocks, 256, 0, stream>>>(
            qweight, qzeros, scales, W_w, x, X_w, I, G, dqBlocks, nwords);
        dim3 grid(O / 256, M / 256);
        gemm_bf16_256<<<grid, dim3(512), 0, stream>>>(
            (const ushort*)X_w, (const ushort*)W_w, bias, out, M, O, I);
    } else {
        dim3 grid(O / BN, M / BM);
        awq_gemm_fused<<<grid, dim3(256), 0, stream>>>(
            x, qweight, qzeros, scales, bias, out, M, O, I, G);
    }
}